// Round 8
// baseline (543.849 us; speedup 1.0000x reference)
//
#include <hip/hip_runtime.h>
#include <hip/hip_bf16.h>

// ---------------------------------------------------------------------------
// GAT (2-layer) on MI355X. fp32 tensors, adj int32. N = 8192, D = 64.
//   k_pack   : stream raw adj (256 MB) once -> 8 MB bitmask.
//   k_prep*  : Wh = x@W^T+b -> WhT (bf16 [feature][node]) + s,d + exp tables.
//   k_agg_l* : masked-softmax aggregation, MFMA 16x16x32 bf16.
//              NS=8 K-splits, KR=1024 per block as 4 chunks of 256:
//              chunk c+1 is prefetched into REGISTERS while chunk c computes
//              from LDS (global latency hidden), then reg->LDS + barrier.
//              Epilogue: LDS transpose, contiguous 16 KB tile store (round 7).
//   k_out    : out = relu(sum(numP)/sum(denP)) @ out_w^T + out_b (fp32).
// Workspace ~28 MB. No atomics, no memsets.
// ---------------------------------------------------------------------------

typedef __attribute__((ext_vector_type(8))) __bf16 bf16x8;
typedef __attribute__((ext_vector_type(4))) float  f32x4;

union Frag {
    bf16x8         v;
    unsigned int   w[4];
    unsigned short h[8];
};

union BF2 {
    __hip_bfloat162 b;
    unsigned int    u;
};

__device__ __forceinline__ unsigned short f2bf(float f) {
    unsigned int u = __float_as_uint(f);
    u += 0x7FFFu + ((u >> 16) & 1u);          // round-to-nearest-even
    return (unsigned short)(u >> 16);
}

// ------------------------- adj -> bitmask streaming ------------------------
__global__ __launch_bounds__(256) void k_pack(
    const int* __restrict__ adj, unsigned long long* __restrict__ bits)
{
    int wgid = blockIdx.x * 4 + (threadIdx.x >> 6);
    int lane = threadIdx.x & 63;
    const long long NW  = 2048LL * 4;
    const long long TOT = 8192LL * 8192;
    for (long long base = (long long)wgid * 512; base < TOT; base += NW * 512) {
        int a[8];
#pragma unroll
        for (int i = 0; i < 8; i++) a[i] = adj[base + i * 64 + lane];
        unsigned long long m[8];
#pragma unroll
        for (int i = 0; i < 8; i++) m[i] = __ballot(a[i] != 0);
        if (lane < 4) {
            reinterpret_cast<ulonglong2*>(bits + (base >> 6))[lane] =
                ulonglong2{m[2 * lane], m[2 * lane + 1]};
        }
    }
}

// ------------------------------- prep --------------------------------------
__device__ __forceinline__ void prep_tail(
    float (*xs)[65], float (*Wt)[65], float (*sred)[64], float (*dred)[64],
    const float* __restrict__ W, const float* __restrict__ bias,
    const float* __restrict__ avec,
    unsigned short* __restrict__ WhT,
    float* __restrict__ sraw, float* __restrict__ draw,
    float* __restrict__ E1, float* __restrict__ E2,
    float* __restrict__ F1, float* __restrict__ F2,
    int tid, int r0)
{
    for (int e = tid; e < 4096; e += 256) {
        int o = e >> 6, c = e & 63;
        Wt[c][o] = W[e];                       // W[o][c] -> transposed LDS
    }
    __syncthreads();

    int r = tid & 63, chunk = tid >> 6, c0 = chunk * 16;
    float acc[16];
#pragma unroll
    for (int o = 0; o < 16; o++) acc[o] = bias[c0 + o];
    for (int c = 0; c < 64; c++) {
        float xv = xs[r][c];
#pragma unroll
        for (int o = 0; o < 16; o++) acc[o] += xv * Wt[c][c0 + o];
    }

    float sp = 0.f, dp = 0.f;
#pragma unroll
    for (int o = 0; o < 16; o++) {
        sp += acc[o] * avec[c0 + o];           // a[:64]
        dp += acc[o] * avec[64 + c0 + o];      // a[64:]
    }
    sred[chunk][r] = sp;
    dred[chunk][r] = dp;

#pragma unroll
    for (int o = 0; o < 16; o++)
        WhT[(c0 + o) * 8192 + r0 + r] = f2bf(acc[o]);

    __syncthreads();
    if (tid < 64) {
        int g = r0 + tid;
        float s = sred[0][tid] + sred[1][tid] + sred[2][tid] + sred[3][tid];
        float d = dred[0][tid] + dred[1][tid] + dred[2][tid] + dred[3][tid];
        sraw[g] = s;  E1[g] = __expf(s);  E2[g] = __expf(0.2f * s);
        draw[g] = d;  F1[g] = __expf(d);  F2[g] = __expf(0.2f * d);
    }
}

__global__ __launch_bounds__(256) void k_prep0(
    const float* __restrict__ ue, const float* __restrict__ ie,
    const float* __restrict__ W, const float* __restrict__ bias,
    const float* __restrict__ avec,
    unsigned short* __restrict__ WhT,
    float* __restrict__ sraw, float* __restrict__ draw,
    float* __restrict__ E1, float* __restrict__ E2,
    float* __restrict__ F1, float* __restrict__ F2)
{
    __shared__ float xs[64][65];
    __shared__ float Wt[64][65];
    __shared__ float sred[4][64];
    __shared__ float dred[4][64];
    int tid = threadIdx.x, r0 = blockIdx.x * 64;

    for (int e = tid; e < 4096; e += 256) {
        int r = e >> 6, c = e & 63;
        int row = r0 + r;
        xs[r][c] = (row < 4096) ? ue[row * 64 + c] : ie[(row - 4096) * 64 + c];
    }
    prep_tail(xs, Wt, sred, dred, W, bias, avec, WhT, sraw, draw,
              E1, E2, F1, F2, tid, r0);
}

// numP layout: [ks][rowblk][64*64] tiles; denP: [ks][8192].
template <int NS>
__global__ __launch_bounds__(256) void k_prep1(
    const float* __restrict__ numP, const float* __restrict__ denP,
    const float* __restrict__ W, const float* __restrict__ bias,
    const float* __restrict__ avec,
    unsigned short* __restrict__ WhT,
    float* __restrict__ sraw, float* __restrict__ draw,
    float* __restrict__ E1, float* __restrict__ E2,
    float* __restrict__ F1, float* __restrict__ F2)
{
    __shared__ float xs[64][65];
    __shared__ float Wt[64][65];
    __shared__ float sred[4][64];
    __shared__ float dred[4][64];
    __shared__ float dtot[64];
    int tid = threadIdx.x, r0 = blockIdx.x * 64;
    int rowblk = blockIdx.x;

    if (tid < 64) {
        float s = 0.f;
#pragma unroll
        for (int p = 0; p < NS; p++) s += denP[p * 8192 + r0 + tid];
        dtot[tid] = fmaxf(s, 1e-20f);
    }
    __syncthreads();
    for (int e = tid; e < 4096; e += 256) {
        int r = e >> 6;
        float s = 0.f;
#pragma unroll
        for (int p = 0; p < NS; p++)
            s += numP[(size_t)(p * 128 + rowblk) * 4096 + e];
        float v = s / dtot[r];
        xs[r][e & 63] = v > 0.f ? v : 0.f;
    }
    prep_tail(xs, Wt, sred, dred, W, bias, avec, WhT, sraw, draw,
              E1, E2, F1, F2, tid, r0);
}

// --------------------------- aggregation (core) ----------------------------
// grid (128, 8): 64-row block x 1024-k split, processed as 4 chunks of 256.
// Registers double-buffer the staging; LDS single-buffered (38.9 KB).
struct AggSmem {
    union {
        unsigned short WhB[64][264];           // 33 KB, live during K loop
        struct {
            float T[64][68];                   // 17.4 KB, live after K loop
            float denT[64];
        } ep;
    } u;
    float dvL[256], f1L[256], f2L[256];
    unsigned int mkL[64][8];
};

struct Pref {
    uint4 w[8];                                 // WhB slice (32 KB / 256 thr)
    float dv, f1, f2;                           // tables (1 elem/thread)
    unsigned int mk[2];                         // masks  (2 dwords/thread)
};

__device__ __forceinline__ void pref_load(
    Pref& P, int tid, int rowblk, int kc,
    const unsigned short* __restrict__ WhT,
    const float* __restrict__ draw,
    const float* __restrict__ F1v, const float* __restrict__ F2v,
    const unsigned int* __restrict__ bits32)
{
#pragma unroll
    for (int i = 0; i < 8; i++) {
        int p = tid + 256 * i, f = p >> 5, c8 = (p & 31) * 8;
        P.w[i] = *reinterpret_cast<const uint4*>(WhT + (size_t)f * 8192 + kc + c8);
    }
    P.dv = draw[kc + tid];
    P.f1 = F1v[kc + tid];
    P.f2 = F2v[kc + tid];
    int kw = kc >> 5;
#pragma unroll
    for (int j = 0; j < 2; j++) {
        int p = tid + 256 * j;
        P.mk[j] = bits32[(rowblk * 64 + (p >> 3)) * 256 + kw + (p & 7)];
    }
}

__device__ __forceinline__ void pref_store(const Pref& P, AggSmem& sm, int tid)
{
#pragma unroll
    for (int i = 0; i < 8; i++) {
        int p = tid + 256 * i, f = p >> 5, c8 = (p & 31) * 8;
        *reinterpret_cast<uint4*>(&sm.u.WhB[f][c8]) = P.w[i];
    }
    sm.dvL[tid] = P.dv;
    sm.f1L[tid] = P.f1;
    sm.f2L[tid] = P.f2;
#pragma unroll
    for (int j = 0; j < 2; j++) {
        int p = tid + 256 * j;
        sm.mkL[p >> 3][p & 7] = P.mk[j];
    }
}

__device__ __forceinline__ void agg_body(
    const unsigned int* __restrict__ bits32,
    const unsigned short* __restrict__ WhT,
    const float* __restrict__ sraw,
    const float* __restrict__ E1v, const float* __restrict__ E2v,
    const float* __restrict__ draw,
    const float* __restrict__ F1v, const float* __restrict__ F2v,
    float* __restrict__ numP, float* __restrict__ denP)
{
    constexpr int CK = 256, NCH = 4;           // 1024 k per block
    __shared__ AggSmem sm;

    int tid  = threadIdx.x;
    int wave = tid >> 6, lane = tid & 63;
    int quad = lane >> 4, l16 = lane & 15;
    int rowblk = blockIdx.x, ks = blockIdx.y;
    int k0  = ks * (CK * NCH);

    Pref P;
    pref_load(P, tid, rowblk, k0, WhT, draw, F1v, F2v, bits32);
    pref_store(P, sm, tid);
    __syncthreads();

    int row = rowblk * 64 + wave * 16 + l16;
    float sv = sraw[row], e1 = E1v[row], e2 = E2v[row];

    f32x4 accs[4];
    f32x4 accd = {0.f, 0.f, 0.f, 0.f};
#pragma unroll
    for (int nt = 0; nt < 4; nt++) accs[nt] = accd;

    Frag ones;
    ones.w[0] = ones.w[1] = ones.w[2] = ones.w[3] = 0x3F803F80u;  // bf16 1.0

    int lrow = wave * 16 + l16;

    for (int c = 0; c < NCH; c++) {
        if (c + 1 < NCH)                       // issue next chunk's loads now;
            pref_load(P, tid, rowblk, k0 + (c + 1) * CK,
                      WhT, draw, F1v, F2v, bits32);   // waited on only at store

#pragma unroll 2
        for (int kb = 0; kb < CK; kb += 32) {
            int kq = kb + quad * 8;

            unsigned int mask8 = (sm.mkL[lrow][kb >> 5] >> (quad * 8)) & 0xFFu;
            float4 dd0 = *reinterpret_cast<const float4*>(&sm.dvL[kq]);
            float4 dd1 = *reinterpret_cast<const float4*>(&sm.dvL[kq + 4]);
            float4 fa0 = *reinterpret_cast<const float4*>(&sm.f1L[kq]);
            float4 fa1 = *reinterpret_cast<const float4*>(&sm.f1L[kq + 4]);
            float4 fb0 = *reinterpret_cast<const float4*>(&sm.f2L[kq]);
            float4 fb1 = *reinterpret_cast<const float4*>(&sm.f2L[kq + 4]);
            float dva[8] = {dd0.x, dd0.y, dd0.z, dd0.w, dd1.x, dd1.y, dd1.z, dd1.w};
            float f1a[8] = {fa0.x, fa0.y, fa0.z, fa0.w, fa1.x, fa1.y, fa1.z, fa1.w};
            float f2a[8] = {fb0.x, fb0.y, fb0.z, fb0.w, fb1.x, fb1.y, fb1.z, fb1.w};

            Frag A;
#pragma unroll
            for (int p = 0; p < 4; p++) {
                float w2[2];
#pragma unroll
                for (int h = 0; h < 2; h++) {
                    int j = 2 * p + h;
                    float t   = sv + dva[j];
                    bool  neg = t < 0.f;
                    float ww  = (neg ? e2 : e1) * (neg ? f2a[j] : f1a[j]);
                    w2[h] = ((mask8 >> j) & 1u) ? ww : 0.f;
                }
                BF2 cv;
                cv.b = __float22bfloat162_rn(float2{w2[0], w2[1]});
                A.w[p] = cv.u;
            }

#pragma unroll
            for (int nt = 0; nt < 4; nt++) {
                Frag B;
                B.v = *reinterpret_cast<const bf16x8*>(&sm.u.WhB[nt * 16 + l16][kq]);
                accs[nt] = __builtin_amdgcn_mfma_f32_16x16x32_bf16(A.v, B.v,
                                                                   accs[nt], 0, 0, 0);
            }
            accd = __builtin_amdgcn_mfma_f32_16x16x32_bf16(A.v, ones.v, accd, 0, 0, 0);
        }

        if (c + 1 < NCH) {
            __syncthreads();                   // everyone done reading chunk c
            pref_store(P, sm, tid);            // vm-wait lands here, not earlier
            __syncthreads();                   // chunk c+1 visible
        }
    }

    // ---- epilogue: transpose through LDS, contiguous tile store ----
    __syncthreads();                            // WhB dead after this point
#pragma unroll
    for (int rr = 0; rr < 4; rr++) {
        int r = wave * 16 + quad * 4 + rr;
#pragma unroll
        for (int nt = 0; nt < 4; nt++)
            sm.u.ep.T[r][nt * 16 + l16] = accs[nt][rr];
        if (l16 == 0) sm.u.ep.denT[r] = accd[rr];
    }
    __syncthreads();

    float* dst = numP + (size_t)(ks * 128 + rowblk) * 4096;
#pragma unroll
    for (int i = 0; i < 4; i++) {
        int idx = i * 1024 + tid * 4;
        int r = idx >> 6, c2 = idx & 63;
        float4 v = *reinterpret_cast<const float4*>(&sm.u.ep.T[r][c2]);
        *reinterpret_cast<float4*>(dst + idx) = v;
    }
    if (tid < 64)
        denP[ks * 8192 + rowblk * 64 + tid] = sm.u.ep.denT[tid];
}

__global__ __launch_bounds__(256) void k_agg_l0(
    const unsigned int* __restrict__ bits32, const unsigned short* __restrict__ WhT,
    const float* __restrict__ sraw,
    const float* __restrict__ E1v, const float* __restrict__ E2v,
    const float* __restrict__ draw,
    const float* __restrict__ F1v, const float* __restrict__ F2v,
    float* __restrict__ numP, float* __restrict__ denP)
{
    agg_body(bits32, WhT, sraw, E1v, E2v, draw, F1v, F2v, numP, denP);
}

__global__ __launch_bounds__(256) void k_agg_l1(
    const unsigned int* __restrict__ bits32, const unsigned short* __restrict__ WhT,
    const float* __restrict__ sraw,
    const float* __restrict__ E1v, const float* __restrict__ E2v,
    const float* __restrict__ draw,
    const float* __restrict__ F1v, const float* __restrict__ F2v,
    float* __restrict__ numP, float* __restrict__ denP)
{
    agg_body(bits32, WhT, sraw, E1v, E2v, draw, F1v, F2v, numP, denP);
}

// ----------------------------- output GEMM ---------------------------------
template <int NS>
__global__ __launch_bounds__(256) void k_out(
    const float* __restrict__ numP, const float* __restrict__ denP,
    const float* __restrict__ W, const float* __restrict__ bias,
    float* __restrict__ out)
{
    __shared__ float xs[64][65];
    __shared__ float Wt[64][65];
    __shared__ float dtot[64];
    int tid = threadIdx.x, r0 = blockIdx.x * 64;
    int rowblk = blockIdx.x;

    if (tid < 64) {
        float s = 0.f;
#pragma unroll
        for (int p = 0; p < NS; p++) s += denP[p * 8192 + r0 + tid];
        dtot[tid] = fmaxf(s, 1e-20f);
    }
    __syncthreads();
    for (int e = tid; e < 4096; e += 256) {
        int r = e >> 6;
        float s = 0.f;
#pragma unroll
        for (int p = 0; p < NS; p++)
            s += numP[(size_t)(p * 128 + rowblk) * 4096 + e];
        float v = s / dtot[r];
        xs[r][e & 63] = v > 0.f ? v : 0.f;
    }
    for (int e = tid; e < 4096; e += 256) {
        int o = e >> 6, c = e & 63;
        Wt[c][o] = W[e];
    }
    __syncthreads();

    int r = tid & 63, chunk = tid >> 6, c0 = chunk * 16;
    float acc[16];
#pragma unroll
    for (int o = 0; o < 16; o++) acc[o] = bias[c0 + o];
    for (int c = 0; c < 64; c++) {
        float xv = xs[r][c];
#pragma unroll
        for (int o = 0; o < 16; o++) acc[o] += xv * Wt[c][c0 + o];
    }
#pragma unroll
    for (int o = 0; o < 16; o++)
        out[(r0 + r) * 64 + c0 + o] = acc[o];
}

// ------------------------------- launch ------------------------------------
extern "C" void kernel_launch(void* const* d_in, const int* in_sizes, int n_in,
                              void* d_out, int out_size, void* d_ws, size_t ws_size,
                              hipStream_t stream)
{
    const int*   adj = (const int*)d_in[0];
    const float* ue  = (const float*)d_in[1];
    const float* ie  = (const float*)d_in[2];
    const float* W0w = (const float*)d_in[3];
    const float* W0b = (const float*)d_in[4];
    const float* a0  = (const float*)d_in[5];
    const float* W1w = (const float*)d_in[6];
    const float* W1b = (const float*)d_in[7];
    const float* a1  = (const float*)d_in[8];
    const float* Ow  = (const float*)d_in[9];
    const float* Ob  = (const float*)d_in[10];

    constexpr int NS = 8;

    char* ws = (char*)d_ws;
    size_t off = 0;
    auto alloc = [&](size_t bytes) -> char* {
        char* p = ws + off;
        off += (bytes + 255) & ~(size_t)255;
        return p;
    };
    float*          numP    = (float*)alloc((size_t)NS * 524288 * 4);   // 16 MB
    float*          denP    = (float*)alloc((size_t)NS * 8192 * 4);     // 256 KB
    unsigned long long* adjbits = (unsigned long long*)alloc(8192 * 1024);  // 8 MB
    unsigned short* WhT0    = (unsigned short*)alloc(64 * 8192 * 2);    // 1 MB
    unsigned short* WhT1    = (unsigned short*)alloc(64 * 8192 * 2);    // 1 MB
    float* sr0 = (float*)alloc(8192 * 4); float* dr0 = (float*)alloc(8192 * 4);
    float* E10 = (float*)alloc(8192 * 4); float* E20 = (float*)alloc(8192 * 4);
    float* F10 = (float*)alloc(8192 * 4); float* F20 = (float*)alloc(8192 * 4);
    float* sr1 = (float*)alloc(8192 * 4); float* dr1 = (float*)alloc(8192 * 4);
    float* E11 = (float*)alloc(8192 * 4); float* E21 = (float*)alloc(8192 * 4);
    float* F11 = (float*)alloc(8192 * 4); float* F21 = (float*)alloc(8192 * 4);

    const unsigned int* bits32 = (const unsigned int*)adjbits;

    // stream adj -> bitmask (the only full 256 MB read of the pipeline)
    k_pack<<<2048, 256, 0, stream>>>(adj, adjbits);

    // layer 0
    k_prep0<<<128, 256, 0, stream>>>(ue, ie, W0w, W0b, a0, WhT0,
                                     sr0, dr0, E10, E20, F10, F20);
    k_agg_l0<<<dim3(128, NS), 256, 0, stream>>>(bits32, WhT0, sr0, E10, E20,
                                                dr0, F10, F20, numP, denP);
    // layer 1
    k_prep1<NS><<<128, 256, 0, stream>>>(numP, denP, W1w, W1b, a1, WhT1,
                                         sr1, dr1, E11, E21, F11, F21);
    k_agg_l1<<<dim3(128, NS), 256, 0, stream>>>(bits32, WhT1, sr1, E11, E21,
                                                dr1, F11, F21, numP, denP);
    // output projection
    k_out<NS><<<128, 256, 0, stream>>>(numP, denP, Ow, Ob, (float*)d_out);
}

// Round 10
// 514.448 us; speedup vs baseline: 1.0571x; 1.0571x over previous
//
#include <hip/hip_runtime.h>

// ---------------------------------------------------------------------------
// GAT (2-layer) on MI355X. fp32 tensors, adj int32. N = 8192, D = 64.
//   k_prep*  : Wh = x@W^T+b -> WhT (f16 [feature][node]) + f16 exp tables:
//              per-row E12 = {e^s, e^0.2s} packed, per-col F1h = e^d, F2h = e^0.2d.
//   k_agg<RAW>: masked-softmax aggregation, MFMA 16x16x32 f16.
//              Key identity: exp(leaky_relu(s+d)) = max(e^s e^d, e^.2s e^.2d)
//              -> A-fragment built with v_pk_mul_f16 x2 + v_pk_max_f16 + bit-AND
//              mask. No transcendentals, no compares, no cvt in the loop.
//              RAW=1: phase-1 streams raw adj (256 KB/block) via __ballot into
//              LDS mask table + writes 8 MB bitmask for layer 1.
//              RAW=0: phase-1 loads the 8 MB bitmask.
//              K split 8-way; 8 chunks of 128 k, register double-buffered
//              WhT staging; epilogue LDS-transpose + contiguous tile store.
//   k_out    : out = relu(sum(numP)/sum(denP)) @ out_w^T + out_b (fp32).
// Workspace ~27 MB. No atomics, no memsets.
// ---------------------------------------------------------------------------

typedef _Float16 f16x8 __attribute__((ext_vector_type(8)));
typedef _Float16 f16x2 __attribute__((ext_vector_type(2)));
typedef __attribute__((ext_vector_type(4))) float f32x4;

union Frag16 {
    f16x8        v;
    unsigned int u[4];
};
union HV2 {
    f16x2        v;
    _Float16     h[2];
    unsigned int u;
};

// ------------------------------- prep --------------------------------------
__device__ __forceinline__ void prep_tail(
    float (*xs)[65], float (*Wt)[65], float (*sred)[64], float (*dred)[64],
    const float* __restrict__ W, const float* __restrict__ bias,
    const float* __restrict__ avec,
    _Float16* __restrict__ WhT,
    unsigned int* __restrict__ E12,
    _Float16* __restrict__ F1h, _Float16* __restrict__ F2h,
    int tid, int r0)
{
    for (int e = tid; e < 4096; e += 256) {
        int o = e >> 6, c = e & 63;
        Wt[c][o] = W[e];                       // W[o][c] -> transposed LDS
    }
    __syncthreads();

    int r = tid & 63, chunk = tid >> 6, c0 = chunk * 16;
    float acc[16];
#pragma unroll
    for (int o = 0; o < 16; o++) acc[o] = bias[c0 + o];
    for (int c = 0; c < 64; c++) {
        float xv = xs[r][c];
#pragma unroll
        for (int o = 0; o < 16; o++) acc[o] += xv * Wt[c][c0 + o];
    }

    float sp = 0.f, dp = 0.f;
#pragma unroll
    for (int o = 0; o < 16; o++) {
        sp += acc[o] * avec[c0 + o];           // a[:64]
        dp += acc[o] * avec[64 + c0 + o];      // a[64:]
    }
    sred[chunk][r] = sp;
    dred[chunk][r] = dp;

#pragma unroll
    for (int o = 0; o < 16; o++)
        WhT[(size_t)(c0 + o) * 8192 + r0 + r] = (_Float16)acc[o];

    __syncthreads();
    if (tid < 64) {
        int g = r0 + tid;
        float s = sred[0][tid] + sred[1][tid] + sred[2][tid] + sred[3][tid];
        float d = dred[0][tid] + dred[1][tid] + dred[2][tid] + dred[3][tid];
        HV2 e;
        e.h[0] = (_Float16)__expf(s);          // e^s       (lo)
        e.h[1] = (_Float16)__expf(0.2f * s);   // e^{0.2s}  (hi)
        E12[g] = e.u;
        F1h[g] = (_Float16)__expf(d);
        F2h[g] = (_Float16)__expf(0.2f * d);
    }
}

__global__ __launch_bounds__(256) void k_prep0(
    const float* __restrict__ ue, const float* __restrict__ ie,
    const float* __restrict__ W, const float* __restrict__ bias,
    const float* __restrict__ avec,
    _Float16* __restrict__ WhT, unsigned int* __restrict__ E12,
    _Float16* __restrict__ F1h, _Float16* __restrict__ F2h)
{
    __shared__ float xs[64][65];
    __shared__ float Wt[64][65];
    __shared__ float sred[4][64];
    __shared__ float dred[4][64];
    int tid = threadIdx.x, r0 = blockIdx.x * 64;

    for (int e = tid; e < 4096; e += 256) {
        int r = e >> 6, c = e & 63;
        int row = r0 + r;
        xs[r][c] = (row < 4096) ? ue[row * 64 + c] : ie[(row - 4096) * 64 + c];
    }
    prep_tail(xs, Wt, sred, dred, W, bias, avec, WhT, E12, F1h, F2h, tid, r0);
}

// numP layout: [ks][rowblk][64*64] tiles; denP: [ks][8192].
template <int NS>
__global__ __launch_bounds__(256) void k_prep1(
    const float* __restrict__ numP, const float* __restrict__ denP,
    const float* __restrict__ W, const float* __restrict__ bias,
    const float* __restrict__ avec,
    _Float16* __restrict__ WhT, unsigned int* __restrict__ E12,
    _Float16* __restrict__ F1h, _Float16* __restrict__ F2h)
{
    __shared__ float xs[64][65];
    __shared__ float Wt[64][65];
    __shared__ float sred[4][64];
    __shared__ float dred[4][64];
    __shared__ float dtot[64];
    int tid = threadIdx.x, r0 = blockIdx.x * 64;
    int rowblk = blockIdx.x;

    if (tid < 64) {
        float s = 0.f;
#pragma unroll
        for (int p = 0; p < NS; p++) s += denP[p * 8192 + r0 + tid];
        dtot[tid] = fmaxf(s, 1e-20f);
    }
    __syncthreads();
    for (int e = tid; e < 4096; e += 256) {
        int r = e >> 6;
        float s = 0.f;
#pragma unroll
        for (int p = 0; p < NS; p++)
            s += numP[(size_t)(p * 128 + rowblk) * 4096 + e];
        float v = s / dtot[r];
        xs[r][e & 63] = v > 0.f ? v : 0.f;
    }
    prep_tail(xs, Wt, sred, dred, W, bias, avec, WhT, E12, F1h, F2h, tid, r0);
}

// --------------------------- aggregation (core) ----------------------------
// grid (128, 8): 64-row block x 1024-k split, 8 chunks of 128 k.
// A-frag: lane(l16,quad) holds A[m=l16][k=quad*8+j]; C/D row=quad*4+reg,col=l16.
struct AggSmem {
    union {
        _Float16 WhB[64][136];                 // 17408 B, live during K loop
        struct {
            float T[64][68];                   // epilogue transpose
            float denT[64];
        } ep;                                  // 17664 B
    } u;
    unsigned int mkAll[64][36];                // 9216 B (32 words used, pad 36)
    unsigned int f1All[512];                   // 1024 halves = 2048 B
    unsigned int f2All[512];                   // 2048 B
};                                             // ~31 KB -> 5 blocks/CU capacity

template <int RAW>
__global__ __launch_bounds__(256) void k_agg(
    const int* __restrict__ adj, unsigned int* __restrict__ bits,
    const _Float16* __restrict__ WhT, const unsigned int* __restrict__ E12,
    const _Float16* __restrict__ F1h, const _Float16* __restrict__ F2h,
    float* __restrict__ numP, float* __restrict__ denP)
{
    constexpr int CK = 128, NCH = 8;           // 1024 k per block
    __shared__ AggSmem sm;

    int tid  = threadIdx.x;
    int wave = tid >> 6, lane = tid & 63;
    int quad = lane >> 4, l16 = lane & 15;
    int rowblk = blockIdx.x, ks = blockIdx.y;
    int k0 = ks * (CK * NCH);

    // ---- phase 1: masks for the whole block region into LDS ----
    if constexpr (RAW) {
        // stream 64 rows x 1024 cols of adj; ballot -> mask words
        for (int r = 0; r < 16; r++) {
            int row_l = wave * 16 + r;
            const int* ap = adj + (size_t)(rowblk * 64 + row_l) * 8192 + k0 + lane;
            int a[16];
#pragma unroll
            for (int g = 0; g < 16; g++) a[g] = ap[g * 64];
            unsigned long long mb[16];
#pragma unroll
            for (int g = 0; g < 16; g++) mb[g] = __ballot(a[g] != 0);
            if (lane == 0) {
#pragma unroll
                for (int g = 0; g < 16; g++) {
                    sm.mkAll[row_l][2 * g]     = (unsigned int)mb[g];
                    sm.mkAll[row_l][2 * g + 1] = (unsigned int)(mb[g] >> 32);
                }
            }
        }
        __syncthreads();
        // write bitmask to global for layer 1 (128 B contiguous per row)
        for (int t = tid; t < 512; t += 256) {
            int row_l = t >> 3, w4 = (t & 7) * 4;
            uint4 v = *reinterpret_cast<const uint4*>(&sm.mkAll[row_l][w4]);
            *reinterpret_cast<uint4*>(
                bits + (size_t)(rowblk * 64 + row_l) * 256 + ks * 32 + w4) = v;
        }
    } else {
        for (int t = tid; t < 512; t += 256) {
            int row_l = t >> 3, w4 = (t & 7) * 4;
            uint4 v = *reinterpret_cast<const uint4*>(
                bits + (size_t)(rowblk * 64 + row_l) * 256 + ks * 32 + w4);
            *reinterpret_cast<uint4*>(&sm.mkAll[row_l][w4]) = v;
        }
    }
    // ---- exp tables for the whole 1024-k range ----
    if (tid < 128) {
        uint4 v = *reinterpret_cast<const uint4*>(F1h + k0 + tid * 8);
        *reinterpret_cast<uint4*>(&sm.f1All[tid * 4]) = v;
    } else {
        int t2 = tid - 128;
        uint4 v = *reinterpret_cast<const uint4*>(F2h + k0 + t2 * 8);
        *reinterpret_cast<uint4*>(&sm.f2All[t2 * 4]) = v;
    }

    // ---- first chunk WhT staging ----
    uint4 P[4];
#pragma unroll
    for (int i = 0; i < 4; i++) {
        int p = tid + 256 * i, f = p >> 4, c8 = (p & 15) * 8;
        P[i] = *reinterpret_cast<const uint4*>(WhT + (size_t)f * 8192 + k0 + c8);
    }
#pragma unroll
    for (int i = 0; i < 4; i++) {
        int p = tid + 256 * i, f = p >> 4, c8 = (p & 15) * 8;
        *reinterpret_cast<uint4*>(&sm.u.WhB[f][c8]) = P[i];
    }
    __syncthreads();

    int row = rowblk * 64 + wave * 16 + l16;
    int lrow = wave * 16 + l16;
    unsigned int e12 = E12[row];
    HV2 e1p, e2p;
    e1p.u = (e12 & 0xFFFFu);  e1p.u |= e1p.u << 16;   // {e^s, e^s}
    e2p.u = (e12 >> 16);      e2p.u |= e2p.u << 16;   // {e^.2s, e^.2s}

    f32x4 accs[4];
    f32x4 accd = {0.f, 0.f, 0.f, 0.f};
#pragma unroll
    for (int nt = 0; nt < 4; nt++) accs[nt] = accd;

    Frag16 ones;
    ones.u[0] = ones.u[1] = ones.u[2] = ones.u[3] = 0x3C003C00u;  // f16 1.0

    for (int c = 0; c < NCH; c++) {
        if (c + 1 < NCH) {                     // prefetch next chunk's WhT
            int kc = k0 + (c + 1) * CK;
#pragma unroll
            for (int i = 0; i < 4; i++) {
                int p = tid + 256 * i, f = p >> 4, c8 = (p & 15) * 8;
                P[i] = *reinterpret_cast<const uint4*>(
                    WhT + (size_t)f * 8192 + kc + c8);
            }
        }

#pragma unroll
        for (int kb = 0; kb < CK; kb += 32) {
            int kq = kb + quad * 8;
            unsigned int word = sm.mkAll[lrow][c * 4 + (kb >> 5)];
            unsigned int w8 = word >> (quad * 8);

            int fidx = (c * CK + kq) >> 1;     // uint index into f tables
            uint4 f1v = *reinterpret_cast<const uint4*>(&sm.f1All[fidx]);
            uint4 f2v = *reinterpret_cast<const uint4*>(&sm.f2All[fidx]);
            unsigned int f1a[4] = {f1v.x, f1v.y, f1v.z, f1v.w};
            unsigned int f2a[4] = {f2v.x, f2v.y, f2v.z, f2v.w};

            Frag16 A;
#pragma unroll
            for (int p = 0; p < 4; p++) {
                HV2 fa, fb, wa;
                fa.u = f1a[p];
                fb.u = f2a[p];
                // exp(lrelu(s+d)) = max(e^s e^d, e^.2s e^.2d)
                // v_pk_mul_f16 x2 + v_pk_max_f16
                wa.v = __builtin_elementwise_max(e1p.v * fa.v, e2p.v * fb.v);
                int s0 = ((int)(w8 << (31 - 2 * p))) >> 31;   // sext bit 2p
                int s1 = ((int)(w8 << (30 - 2 * p))) >> 31;   // sext bit 2p+1
                unsigned int pm = ((unsigned)s0 & 0xFFFFu) | ((unsigned)s1 << 16);
                A.u[p] = wa.u & pm;
            }

#pragma unroll
            for (int nt = 0; nt < 4; nt++) {
                Frag16 B;
                B.v = *reinterpret_cast<const f16x8*>(&sm.u.WhB[nt * 16 + l16][kq]);
                accs[nt] = __builtin_amdgcn_mfma_f32_16x16x32_f16(A.v, B.v,
                                                                  accs[nt], 0, 0, 0);
            }
            accd = __builtin_amdgcn_mfma_f32_16x16x32_f16(A.v, ones.v, accd, 0, 0, 0);
        }

        if (c + 1 < NCH) {
            __syncthreads();                   // done reading chunk c
#pragma unroll
            for (int i = 0; i < 4; i++) {
                int p = tid + 256 * i, f = p >> 4, c8 = (p & 15) * 8;
                *reinterpret_cast<uint4*>(&sm.u.WhB[f][c8]) = P[i];
            }
            __syncthreads();                   // chunk c+1 visible
        }
    }

    // ---- epilogue: transpose through LDS, contiguous tile store ----
    __syncthreads();                            // WhB dead after this point
#pragma unroll
    for (int rr = 0; rr < 4; rr++) {
        int r = wave * 16 + quad * 4 + rr;
#pragma unroll
        for (int nt = 0; nt < 4; nt++)
            sm.u.ep.T[r][nt * 16 + l16] = accs[nt][rr];
        if (l16 == 0) sm.u.ep.denT[r] = accd[rr];
    }
    __syncthreads();

    float* dst = numP + (size_t)(ks * 128 + rowblk) * 4096;
#pragma unroll
    for (int i = 0; i < 4; i++) {
        int idx = i * 1024 + tid * 4;
        int r = idx >> 6, c2 = idx & 63;
        float4 v = *reinterpret_cast<const float4*>(&sm.u.ep.T[r][c2]);
        *reinterpret_cast<float4*>(dst + idx) = v;
    }
    if (tid < 64)
        denP[ks * 8192 + rowblk * 64 + tid] = sm.u.ep.denT[tid];
}

// ----------------------------- output GEMM ---------------------------------
template <int NS>
__global__ __launch_bounds__(256) void k_out(
    const float* __restrict__ numP, const float* __restrict__ denP,
    const float* __restrict__ W, const float* __restrict__ bias,
    float* __restrict__ out)
{
    __shared__ float xs[64][65];
    __shared__ float Wt[64][65];
    __shared__ float dtot[64];
    int tid = threadIdx.x, r0 = blockIdx.x * 64;
    int rowblk = blockIdx.x;

    if (tid < 64) {
        float s = 0.f;
#pragma unroll
        for (int p = 0; p < NS; p++) s += denP[p * 8192 + r0 + tid];
        dtot[tid] = fmaxf(s, 1e-20f);
    }
    __syncthreads();
    for (int e = tid; e < 4096; e += 256) {
        int r = e >> 6;
        float s = 0.f;
#pragma unroll
        for (int p = 0; p < NS; p++)
            s += numP[(size_t)(p * 128 + rowblk) * 4096 + e];
        float v = s / dtot[r];
        xs[r][e & 63] = v > 0.f ? v : 0.f;
    }
    for (int e = tid; e < 4096; e += 256) {
        int o = e >> 6, c = e & 63;
        Wt[c][o] = W[e];
    }
    __syncthreads();

    int r = tid & 63, chunk = tid >> 6, c0 = chunk * 16;
    float acc[16];
#pragma unroll
    for (int o = 0; o < 16; o++) acc[o] = bias[c0 + o];
    for (int c = 0; c < 64; c++) {
        float xv = xs[r][c];
#pragma unroll
        for (int o = 0; o < 16; o++) acc[o] += xv * Wt[c][c0 + o];
    }
#pragma unroll
    for (int o = 0; o < 16; o++)
        out[(r0 + r) * 64 + c0 + o] = acc[o];
}

// ------------------------------- launch ------------------------------------
extern "C" void kernel_launch(void* const* d_in, const int* in_sizes, int n_in,
                              void* d_out, int out_size, void* d_ws, size_t ws_size,
                              hipStream_t stream)
{
    const int*   adj = (const int*)d_in[0];
    const float* ue  = (const float*)d_in[1];
    const float* ie  = (const float*)d_in[2];
    const float* W0w = (const float*)d_in[3];
    const float* W0b = (const float*)d_in[4];
    const float* a0  = (const float*)d_in[5];
    const float* W1w = (const float*)d_in[6];
    const float* W1b = (const float*)d_in[7];
    const float* a1  = (const float*)d_in[8];
    const float* Ow  = (const float*)d_in[9];
    const float* Ob  = (const float*)d_in[10];

    constexpr int NS = 8;

    char* ws = (char*)d_ws;
    size_t off = 0;
    auto alloc = [&](size_t bytes) -> char* {
        char* p = ws + off;
        off += (bytes + 255) & ~(size_t)255;
        return p;
    };
    float*        numP    = (float*)alloc((size_t)NS * 524288 * 4);   // 16 MB
    float*        denP    = (float*)alloc((size_t)NS * 8192 * 4);     // 256 KB
    unsigned int* adjbits = (unsigned int*)alloc(8192 * 1024);        // 8 MB
    _Float16*     WhT0    = (_Float16*)alloc(64 * 8192 * 2);          // 1 MB
    _Float16*     WhT1    = (_Float16*)alloc(64 * 8192 * 2);          // 1 MB
    unsigned int* E12_0   = (unsigned int*)alloc(8192 * 4);
    unsigned int* E12_1   = (unsigned int*)alloc(8192 * 4);
    _Float16* F1h0 = (_Float16*)alloc(8192 * 2);
    _Float16* F2h0 = (_Float16*)alloc(8192 * 2);
    _Float16* F1h1 = (_Float16*)alloc(8192 * 2);
    _Float16* F2h1 = (_Float16*)alloc(8192 * 2);
    // ~27 MB total; every buffer fully overwritten each launch (0xAA-safe).

    // layer 0 (phase-1 streams raw adj, emits bitmask for layer 1)
    k_prep0<<<128, 256, 0, stream>>>(ue, ie, W0w, W0b, a0,
                                     WhT0, E12_0, F1h0, F2h0);
    k_agg<1><<<dim3(128, NS), 256, 0, stream>>>(adj, adjbits, WhT0, E12_0,
                                                F1h0, F2h0, numP, denP);
    // layer 1 (reads bitmask)
    k_prep1<NS><<<128, 256, 0, stream>>>(numP, denP, W1w, W1b, a1,
                                         WhT1, E12_1, F1h1, F2h1);
    k_agg<0><<<dim3(128, NS), 256, 0, stream>>>(adj, adjbits, WhT1, E12_1,
                                                F1h1, F2h1, numP, denP);
    // output projection
    k_out<NS><<<128, 256, 0, stream>>>(numP, denP, Ow, Ob, (float*)d_out);
}

// Round 12
// 510.970 us; speedup vs baseline: 1.0643x; 1.0068x over previous
//
#include <hip/hip_runtime.h>

// ---------------------------------------------------------------------------
// GAT (2-layer) on MI355X. fp32 tensors, adj int32. N = 8192, D = 64.
//   k_pack   : stream raw adj (256 MB) once -> 8 MB bitmask (ballot, 8-deep MLP).
//   k_prep*  : Wh = x@W^T+b -> WhT (f16 [feature][node]) + f16 exp tables.
//   k_agg_l* : masked-softmax aggregation, MFMA 16x16x32 f16.
//              w = exp(lrelu(s+d)) = max(e^s e^d, e^.2s e^.2d): pk_mul x2 +
//              pk_max + bit-AND mask. Both layers read the bitmask only.
//              NS=16 K-splits (512 k/block, 4 chunks of 128), register-
//              prefetched single-buffer LDS staging, stride-138 WhB rows
//              (bank-conflict-free b128 reads), epilogue LDS-transpose +
//              contiguous 16 KB tile store.
//   k_out    : out = relu(sum(numP)/sum(denP)) @ out_w^T + out_b (fp32).
// Workspace ~43 MB. No atomics, no memsets.
// ---------------------------------------------------------------------------

typedef _Float16 f16x8 __attribute__((ext_vector_type(8)));
typedef _Float16 f16x2 __attribute__((ext_vector_type(2)));
typedef __attribute__((ext_vector_type(4))) float f32x4;

union Frag16 {
    f16x8        v;
    unsigned int u[4];
};
union HV2 {
    f16x2        v;
    _Float16     h[2];
    unsigned int u;
};

// ------------------------- adj -> bitmask streaming ------------------------
__global__ __launch_bounds__(256) void k_pack(
    const int* __restrict__ adj, unsigned long long* __restrict__ bits)
{
    int wgid = blockIdx.x * 4 + (threadIdx.x >> 6);
    int lane = threadIdx.x & 63;
    const long long NW  = 2048LL * 4;
    const long long TOT = 8192LL * 8192;
    for (long long base = (long long)wgid * 512; base < TOT; base += NW * 512) {
        int a[8];
#pragma unroll
        for (int i = 0; i < 8; i++) a[i] = adj[base + i * 64 + lane];
        unsigned long long m[8];
#pragma unroll
        for (int i = 0; i < 8; i++) m[i] = __ballot(a[i] != 0);
        if (lane < 4) {
            reinterpret_cast<ulonglong2*>(bits + (base >> 6))[lane] =
                ulonglong2{m[2 * lane], m[2 * lane + 1]};
        }
    }
}

// ------------------------------- prep --------------------------------------
__device__ __forceinline__ void prep_tail(
    float (*xs)[65], float (*Wt)[65], float (*sred)[64], float (*dred)[64],
    const float* __restrict__ W, const float* __restrict__ bias,
    const float* __restrict__ avec,
    _Float16* __restrict__ WhT,
    unsigned int* __restrict__ E12,
    _Float16* __restrict__ F1h, _Float16* __restrict__ F2h,
    int tid, int r0)
{
    for (int e = tid; e < 4096; e += 256) {
        int o = e >> 6, c = e & 63;
        Wt[c][o] = W[e];                       // W[o][c] -> transposed LDS
    }
    __syncthreads();

    int r = tid & 63, chunk = tid >> 6, c0 = chunk * 16;
    float acc[16];
#pragma unroll
    for (int o = 0; o < 16; o++) acc[o] = bias[c0 + o];
    for (int c = 0; c < 64; c++) {
        float xv = xs[r][c];
#pragma unroll
        for (int o = 0; o < 16; o++) acc[o] += xv * Wt[c][c0 + o];
    }

    float sp = 0.f, dp = 0.f;
#pragma unroll
    for (int o = 0; o < 16; o++) {
        sp += acc[o] * avec[c0 + o];           // a[:64]
        dp += acc[o] * avec[64 + c0 + o];      // a[64:]
    }
    sred[chunk][r] = sp;
    dred[chunk][r] = dp;

#pragma unroll
    for (int o = 0; o < 16; o++)
        WhT[(size_t)(c0 + o) * 8192 + r0 + r] = (_Float16)acc[o];

    __syncthreads();
    if (tid < 64) {
        int g = r0 + tid;
        float s = sred[0][tid] + sred[1][tid] + sred[2][tid] + sred[3][tid];
        float d = dred[0][tid] + dred[1][tid] + dred[2][tid] + dred[3][tid];
        HV2 e;
        e.h[0] = (_Float16)__expf(s);          // e^s       (lo)
        e.h[1] = (_Float16)__expf(0.2f * s);   // e^{0.2s}  (hi)
        E12[g] = e.u;
        F1h[g] = (_Float16)__expf(d);
        F2h[g] = (_Float16)__expf(0.2f * d);
    }
}

__global__ __launch_bounds__(256) void k_prep0(
    const float* __restrict__ ue, const float* __restrict__ ie,
    const float* __restrict__ W, const float* __restrict__ bias,
    const float* __restrict__ avec,
    _Float16* __restrict__ WhT, unsigned int* __restrict__ E12,
    _Float16* __restrict__ F1h, _Float16* __restrict__ F2h)
{
    __shared__ float xs[64][65];
    __shared__ float Wt[64][65];
    __shared__ float sred[4][64];
    __shared__ float dred[4][64];
    int tid = threadIdx.x, r0 = blockIdx.x * 64;

    for (int e = tid; e < 4096; e += 256) {
        int r = e >> 6, c = e & 63;
        int row = r0 + r;
        xs[r][c] = (row < 4096) ? ue[row * 64 + c] : ie[(row - 4096) * 64 + c];
    }
    prep_tail(xs, Wt, sred, dred, W, bias, avec, WhT, E12, F1h, F2h, tid, r0);
}

// numP layout: [ks][rowblk][64*64] tiles; denP: [ks][8192].
template <int NS>
__global__ __launch_bounds__(256) void k_prep1(
    const float* __restrict__ numP, const float* __restrict__ denP,
    const float* __restrict__ W, const float* __restrict__ bias,
    const float* __restrict__ avec,
    _Float16* __restrict__ WhT, unsigned int* __restrict__ E12,
    _Float16* __restrict__ F1h, _Float16* __restrict__ F2h)
{
    __shared__ float xs[64][65];
    __shared__ float Wt[64][65];
    __shared__ float sred[4][64];
    __shared__ float dred[4][64];
    __shared__ float dtot[64];
    int tid = threadIdx.x, r0 = blockIdx.x * 64;
    int rowblk = blockIdx.x;

    if (tid < 64) {
        float s = 0.f;
#pragma unroll
        for (int p = 0; p < NS; p++) s += denP[p * 8192 + r0 + tid];
        dtot[tid] = fmaxf(s, 1e-20f);
    }
    __syncthreads();
    for (int e = tid; e < 4096; e += 256) {
        int r = e >> 6;
        float s = 0.f;
#pragma unroll
        for (int p = 0; p < NS; p++)
            s += numP[(size_t)(p * 128 + rowblk) * 4096 + e];
        float v = s / dtot[r];
        xs[r][e & 63] = v > 0.f ? v : 0.f;
    }
    prep_tail(xs, Wt, sred, dred, W, bias, avec, WhT, E12, F1h, F2h, tid, r0);
}

// --------------------------- aggregation (core) ----------------------------
// grid (128, 16): 64-row block x 512-k split, 4 chunks of 128 k.
// WhB stride 138 halves = 69 dw (== 5 mod 32): b128 reads conflict-free.
// Staging indexing (f = p>>4, c8 = (p&15)*8): 64 rows x 128 halves — the
// round-11 regression (p>>3 / (p&7)*8) wrote OOB rows and half columns.
struct AggSmem {
    union {
        _Float16 WhB[64][138];                 // 17664 B, live during K loop
        struct {
            float T[64][68];                   // epilogue transpose
            float denT[64];
        } ep;                                  // 17664 B
    } u;
    unsigned int mkAll[64][20];                // 5120 B (16 words used, pad 20)
    unsigned int f1All[256];                   // 512 halves = 1024 B
    unsigned int f2All[256];                   // 1024 B
};                                             // 24832 B -> 6 blocks/CU

__device__ __forceinline__ void agg_body(
    const unsigned int* __restrict__ bits,
    const _Float16* __restrict__ WhT, const unsigned int* __restrict__ E12,
    const _Float16* __restrict__ F1h, const _Float16* __restrict__ F2h,
    float* __restrict__ numP, float* __restrict__ denP)
{
    constexpr int CK = 128, NCH = 4;           // 512 k per block
    __shared__ AggSmem sm;

    int tid  = threadIdx.x;
    int wave = tid >> 6, lane = tid & 63;
    int quad = lane >> 4, l16 = lane & 15;
    int rowblk = blockIdx.x, ks = blockIdx.y;
    int k0 = ks * (CK * NCH);

    // ---- masks for the block's 64 x 512 region: 16 words/row ----
    {
        int row_l = tid >> 2, w4 = (tid & 3) * 4;
        uint4 v = *reinterpret_cast<const uint4*>(
            bits + (size_t)(rowblk * 64 + row_l) * 256 + ks * 16 + w4);
        *reinterpret_cast<uint4*>(&sm.mkAll[row_l][w4]) = v;
    }
    // ---- exp tables for the 512-k range ----
    if (tid < 64) {
        uint4 v = *reinterpret_cast<const uint4*>(F1h + k0 + tid * 8);
        *reinterpret_cast<uint4*>(&sm.f1All[tid * 4]) = v;
    } else if (tid < 128) {
        int t2 = tid - 64;
        uint4 v = *reinterpret_cast<const uint4*>(F2h + k0 + t2 * 8);
        *reinterpret_cast<uint4*>(&sm.f2All[t2 * 4]) = v;
    }

    // ---- first chunk WhT staging (64 rows x 128 halves = 16 KB) ----
    uint4 P[4];
#pragma unroll
    for (int i = 0; i < 4; i++) {
        int p = tid + 256 * i, f = p >> 4, c8 = (p & 15) * 8;
        P[i] = *reinterpret_cast<const uint4*>(WhT + (size_t)f * 8192 + k0 + c8);
    }
#pragma unroll
    for (int i = 0; i < 4; i++) {
        int p = tid + 256 * i, f = p >> 4, c8 = (p & 15) * 8;
        *reinterpret_cast<uint4*>(&sm.u.WhB[f][c8]) = P[i];
    }
    __syncthreads();

    int row = rowblk * 64 + wave * 16 + l16;
    int lrow = wave * 16 + l16;
    unsigned int e12 = E12[row];
    HV2 e1p, e2p;
    e1p.u = (e12 & 0xFFFFu);  e1p.u |= e1p.u << 16;   // {e^s, e^s}
    e2p.u = (e12 >> 16);      e2p.u |= e2p.u << 16;   // {e^.2s, e^.2s}

    f32x4 accs[4];
    f32x4 accd = {0.f, 0.f, 0.f, 0.f};
#pragma unroll
    for (int nt = 0; nt < 4; nt++) accs[nt] = accd;

    Frag16 ones;
    ones.u[0] = ones.u[1] = ones.u[2] = ones.u[3] = 0x3C003C00u;  // f16 1.0

    for (int c = 0; c < NCH; c++) {
        if (c + 1 < NCH) {                     // prefetch next chunk's WhT
            int kc = k0 + (c + 1) * CK;
#pragma unroll
            for (int i = 0; i < 4; i++) {
                int p = tid + 256 * i, f = p >> 4, c8 = (p & 15) * 8;
                P[i] = *reinterpret_cast<const uint4*>(
                    WhT + (size_t)f * 8192 + kc + c8);
            }
        }

#pragma unroll
        for (int kb = 0; kb < CK; kb += 32) {
            int kq = kb + quad * 8;
            unsigned int word = sm.mkAll[lrow][c * 4 + (kb >> 5)];
            unsigned int w8 = word >> (quad * 8);

            int fidx = (c * CK + kq) >> 1;     // uint index into f tables
            uint4 f1v = *reinterpret_cast<const uint4*>(&sm.f1All[fidx]);
            uint4 f2v = *reinterpret_cast<const uint4*>(&sm.f2All[fidx]);
            unsigned int f1a[4] = {f1v.x, f1v.y, f1v.z, f1v.w};
            unsigned int f2a[4] = {f2v.x, f2v.y, f2v.z, f2v.w};

            Frag16 A;
#pragma unroll
            for (int p = 0; p < 4; p++) {
                HV2 fa, fb, wa;
                fa.u = f1a[p];
                fb.u = f2a[p];
                // exp(lrelu(s+d)) = max(e^s e^d, e^.2s e^.2d)
                wa.v = __builtin_elementwise_max(e1p.v * fa.v, e2p.v * fb.v);
                int s0 = ((int)(w8 << (31 - 2 * p))) >> 31;   // sext bit 2p
                int s1 = ((int)(w8 << (30 - 2 * p))) >> 31;   // sext bit 2p+1
                unsigned int pm = ((unsigned)s0 & 0xFFFFu) | ((unsigned)s1 << 16);
                A.u[p] = wa.u & pm;
            }

#pragma unroll
            for (int nt = 0; nt < 4; nt++) {
                Frag16 B;
                B.v = *reinterpret_cast<const f16x8*>(&sm.u.WhB[nt * 16 + l16][kq]);
                accs[nt] = __builtin_amdgcn_mfma_f32_16x16x32_f16(A.v, B.v,
                                                                  accs[nt], 0, 0, 0);
            }
            accd = __builtin_amdgcn_mfma_f32_16x16x32_f16(A.v, ones.v, accd, 0, 0, 0);
        }

        if (c + 1 < NCH) {
            __syncthreads();                   // done reading chunk c
#pragma unroll
            for (int i = 0; i < 4; i++) {
                int p = tid + 256 * i, f = p >> 4, c8 = (p & 15) * 8;
                *reinterpret_cast<uint4*>(&sm.u.WhB[f][c8]) = P[i];
            }
            __syncthreads();                   // chunk c+1 visible
        }
    }

    // ---- epilogue: transpose through LDS, contiguous tile store ----
    __syncthreads();                            // WhB dead after this point
#pragma unroll
    for (int rr = 0; rr < 4; rr++) {
        int r = wave * 16 + quad * 4 + rr;
#pragma unroll
        for (int nt = 0; nt < 4; nt++)
            sm.u.ep.T[r][nt * 16 + l16] = accs[nt][rr];
        if (l16 == 0) sm.u.ep.denT[r] = accd[rr];
    }
    __syncthreads();

    float* dst = numP + (size_t)(ks * 128 + rowblk) * 4096;
#pragma unroll
    for (int i = 0; i < 4; i++) {
        int idx = i * 1024 + tid * 4;
        int r = idx >> 6, c2 = idx & 63;
        float4 v = *reinterpret_cast<const float4*>(&sm.u.ep.T[r][c2]);
        *reinterpret_cast<float4*>(dst + idx) = v;
    }
    if (tid < 64)
        denP[ks * 8192 + rowblk * 64 + tid] = sm.u.ep.denT[tid];
}

__global__ __launch_bounds__(256) void k_agg_l0(
    const unsigned int* __restrict__ bits,
    const _Float16* __restrict__ WhT, const unsigned int* __restrict__ E12,
    const _Float16* __restrict__ F1h, const _Float16* __restrict__ F2h,
    float* __restrict__ numP, float* __restrict__ denP)
{
    agg_body(bits, WhT, E12, F1h, F2h, numP, denP);
}

__global__ __launch_bounds__(256) void k_agg_l1(
    const unsigned int* __restrict__ bits,
    const _Float16* __restrict__ WhT, const unsigned int* __restrict__ E12,
    const _Float16* __restrict__ F1h, const _Float16* __restrict__ F2h,
    float* __restrict__ numP, float* __restrict__ denP)
{
    agg_body(bits, WhT, E12, F1h, F2h, numP, denP);
}

// ----------------------------- output GEMM ---------------------------------
template <int NS>
__global__ __launch_bounds__(256) void k_out(
    const float* __restrict__ numP, const float* __restrict__ denP,
    const float* __restrict__ W, const float* __restrict__ bias,
    float* __restrict__ out)
{
    __shared__ float xs[64][65];
    __shared__ float Wt[64][65];
    __shared__ float dtot[64];
    int tid = threadIdx.x, r0 = blockIdx.x * 64;
    int rowblk = blockIdx.x;

    if (tid < 64) {
        float s = 0.f;
#pragma unroll
        for (int p = 0; p < NS; p++) s += denP[p * 8192 + r0 + tid];
        dtot[tid] = fmaxf(s, 1e-20f);
    }
    __syncthreads();
    for (int e = tid; e < 4096; e += 256) {
        int r = e >> 6;
        float s = 0.f;
#pragma unroll
        for (int p = 0; p < NS; p++)
            s += numP[(size_t)(p * 128 + rowblk) * 4096 + e];
        float v = s / dtot[r];
        xs[r][e & 63] = v > 0.f ? v : 0.f;
    }
    for (int e = tid; e < 4096; e += 256) {
        int o = e >> 6, c = e & 63;
        Wt[c][o] = W[e];
    }
    __syncthreads();

    int r = tid & 63, chunk = tid >> 6, c0 = chunk * 16;
    float acc[16];
#pragma unroll
    for (int o = 0; o < 16; o++) acc[o] = bias[c0 + o];
    for (int c = 0; c < 64; c++) {
        float xv = xs[r][c];
#pragma unroll
        for (int o = 0; o < 16; o++) acc[o] += xv * Wt[c][c0 + o];
    }
#pragma unroll
    for (int o = 0; o < 16; o++)
        out[(r0 + r) * 64 + c0 + o] = acc[o];
}

// ------------------------------- launch ------------------------------------
extern "C" void kernel_launch(void* const* d_in, const int* in_sizes, int n_in,
                              void* d_out, int out_size, void* d_ws, size_t ws_size,
                              hipStream_t stream)
{
    const int*   adj = (const int*)d_in[0];
    const float* ue  = (const float*)d_in[1];
    const float* ie  = (const float*)d_in[2];
    const float* W0w = (const float*)d_in[3];
    const float* W0b = (const float*)d_in[4];
    const float* a0  = (const float*)d_in[5];
    const float* W1w = (const float*)d_in[6];
    const float* W1b = (const float*)d_in[7];
    const float* a1  = (const float*)d_in[8];
    const float* Ow  = (const float*)d_in[9];
    const float* Ob  = (const float*)d_in[10];

    constexpr int NS = 16;

    char* ws = (char*)d_ws;
    size_t off = 0;
    auto alloc = [&](size_t bytes) -> char* {
        char* p = ws + off;
        off += (bytes + 255) & ~(size_t)255;
        return p;
    };
    float*        numP    = (float*)alloc((size_t)NS * 524288 * 4);   // 32 MB
    float*        denP    = (float*)alloc((size_t)NS * 8192 * 4);     // 512 KB
    unsigned long long* adjbits = (unsigned long long*)alloc(8192 * 1024); // 8 MB
    _Float16*     WhT0    = (_Float16*)alloc(64 * 8192 * 2);          // 1 MB
    _Float16*     WhT1    = (_Float16*)alloc(64 * 8192 * 2);          // 1 MB
    unsigned int* E12_0   = (unsigned int*)alloc(8192 * 4);
    unsigned int* E12_1   = (unsigned int*)alloc(8192 * 4);
    _Float16* F1h0 = (_Float16*)alloc(8192 * 2);
    _Float16* F2h0 = (_Float16*)alloc(8192 * 2);
    _Float16* F1h1 = (_Float16*)alloc(8192 * 2);
    _Float16* F2h1 = (_Float16*)alloc(8192 * 2);
    // ~43 MB total; every buffer fully overwritten each launch (0xAA-safe).

    const unsigned int* bits32 = (const unsigned int*)adjbits;

    // stream adj -> bitmask (the only full 256 MB read of the pipeline)
    k_pack<<<2048, 256, 0, stream>>>(adj, adjbits);

    // layer 0
    k_prep0<<<128, 256, 0, stream>>>(ue, ie, W0w, W0b, a0,
                                     WhT0, E12_0, F1h0, F2h0);
    k_agg_l0<<<dim3(128, NS), 256, 0, stream>>>(bits32, WhT0, E12_0,
                                                F1h0, F2h0, numP, denP);
    // layer 1
    k_prep1<NS><<<128, 256, 0, stream>>>(numP, denP, W1w, W1b, a1,
                                         WhT1, E12_1, F1h1, F2h1);
    k_agg_l1<<<dim3(128, NS), 256, 0, stream>>>(bits32, WhT1, E12_1,
                                                F1h1, F2h1, numP, denP);
    // output projection
    k_out<NS><<<128, 256, 0, stream>>>(numP, denP, Ow, Ob, (float*)d_out);
}

// Round 13
// 477.215 us; speedup vs baseline: 1.1396x; 1.0707x over previous
//
#include <hip/hip_runtime.h>

// ---------------------------------------------------------------------------
// GAT (2-layer) on MI355X. fp32 tensors, adj int32. N = 8192, D = 64.
//   k_pack   : stream raw adj (256 MB) once -> 8 MB bitmask (ballot).
//   k_prep*  : Wh = x@W^T+b -> WhT (f16 [feature][node]) + f16 exp tables.
//   k_agg_l* : masked-softmax aggregation, MFMA 32x32x16 f16.
//              w = exp(lrelu(s+d)) = max(e^s e^d, e^.2s e^.2d): pk_mul x2 +
//              pk_max + bit-AND mask (no transcendental/cmp/cvt in loop).
//              Blocks: 128 rows x 512 k (grid 64x16, zero tail). WhT slice
//              staged in MFMA-FRAGMENT ORDER [k-octet][feature] with +g mod-64
//              rotation: B-fragment ds_reads are contiguous/aligned/conflict-
//              free. Register-prefetched staging, 4 chunks of 128 k.
//              Epilogue: direct stores (32x32 C/D rows are 128 B runs).
//   k_out    : out = relu(sum(numP)/sum(denP)) @ out_w^T + out_b (fp32).
// Workspace ~43 MB. No atomics, no memsets.
// ---------------------------------------------------------------------------

typedef _Float16 f16x8 __attribute__((ext_vector_type(8)));
typedef _Float16 f16x2 __attribute__((ext_vector_type(2)));
typedef float    f32x16 __attribute__((ext_vector_type(16)));

union Frag16 {
    f16x8        v;
    unsigned int u[4];
};
union HV2 {
    f16x2        v;
    _Float16     h[2];
    unsigned int u;
};

// ------------------------- adj -> bitmask streaming ------------------------
__global__ __launch_bounds__(256) void k_pack(
    const int* __restrict__ adj, unsigned long long* __restrict__ bits)
{
    int wgid = blockIdx.x * 4 + (threadIdx.x >> 6);
    int lane = threadIdx.x & 63;
    const long long NW  = 2048LL * 4;
    const long long TOT = 8192LL * 8192;
    for (long long base = (long long)wgid * 512; base < TOT; base += NW * 512) {
        int a[8];
#pragma unroll
        for (int i = 0; i < 8; i++) a[i] = adj[base + i * 64 + lane];
        unsigned long long m[8];
#pragma unroll
        for (int i = 0; i < 8; i++) m[i] = __ballot(a[i] != 0);
        if (lane < 4) {
            reinterpret_cast<ulonglong2*>(bits + (base >> 6))[lane] =
                ulonglong2{m[2 * lane], m[2 * lane + 1]};
        }
    }
}

// ------------------------------- prep --------------------------------------
__device__ __forceinline__ void prep_tail(
    float (*xs)[65], float (*Wt)[65], float (*sred)[64], float (*dred)[64],
    const float* __restrict__ W, const float* __restrict__ bias,
    const float* __restrict__ avec,
    _Float16* __restrict__ WhT,
    unsigned int* __restrict__ E12,
    _Float16* __restrict__ F1h, _Float16* __restrict__ F2h,
    int tid, int r0)
{
    for (int e = tid; e < 4096; e += 256) {
        int o = e >> 6, c = e & 63;
        Wt[c][o] = W[e];                       // W[o][c] -> transposed LDS
    }
    __syncthreads();

    int r = tid & 63, chunk = tid >> 6, c0 = chunk * 16;
    float acc[16];
#pragma unroll
    for (int o = 0; o < 16; o++) acc[o] = bias[c0 + o];
    for (int c = 0; c < 64; c++) {
        float xv = xs[r][c];
#pragma unroll
        for (int o = 0; o < 16; o++) acc[o] += xv * Wt[c][c0 + o];
    }

    float sp = 0.f, dp = 0.f;
#pragma unroll
    for (int o = 0; o < 16; o++) {
        sp += acc[o] * avec[c0 + o];           // a[:64]
        dp += acc[o] * avec[64 + c0 + o];      // a[64:]
    }
    sred[chunk][r] = sp;
    dred[chunk][r] = dp;

#pragma unroll
    for (int o = 0; o < 16; o++)
        WhT[(size_t)(c0 + o) * 8192 + r0 + r] = (_Float16)acc[o];

    __syncthreads();
    if (tid < 64) {
        int g = r0 + tid;
        float s = sred[0][tid] + sred[1][tid] + sred[2][tid] + sred[3][tid];
        float d = dred[0][tid] + dred[1][tid] + dred[2][tid] + dred[3][tid];
        HV2 e;
        e.h[0] = (_Float16)__expf(s);          // e^s       (lo)
        e.h[1] = (_Float16)__expf(0.2f * s);   // e^{0.2s}  (hi)
        E12[g] = e.u;
        F1h[g] = (_Float16)__expf(d);
        F2h[g] = (_Float16)__expf(0.2f * d);
    }
}

__global__ __launch_bounds__(256) void k_prep0(
    const float* __restrict__ ue, const float* __restrict__ ie,
    const float* __restrict__ W, const float* __restrict__ bias,
    const float* __restrict__ avec,
    _Float16* __restrict__ WhT, unsigned int* __restrict__ E12,
    _Float16* __restrict__ F1h, _Float16* __restrict__ F2h)
{
    __shared__ float xs[64][65];
    __shared__ float Wt[64][65];
    __shared__ float sred[4][64];
    __shared__ float dred[4][64];
    int tid = threadIdx.x, r0 = blockIdx.x * 64;

    for (int e = tid; e < 4096; e += 256) {
        int r = e >> 6, c = e & 63;
        int row = r0 + r;
        xs[r][c] = (row < 4096) ? ue[row * 64 + c] : ie[(row - 4096) * 64 + c];
    }
    prep_tail(xs, Wt, sred, dred, W, bias, avec, WhT, E12, F1h, F2h, tid, r0);
}

// numP layout: [ks][rowblk128][128*64] tiles; denP: [ks][8192].
template <int NS>
__global__ __launch_bounds__(256) void k_prep1(
    const float* __restrict__ numP, const float* __restrict__ denP,
    const float* __restrict__ W, const float* __restrict__ bias,
    const float* __restrict__ avec,
    _Float16* __restrict__ WhT, unsigned int* __restrict__ E12,
    _Float16* __restrict__ F1h, _Float16* __restrict__ F2h)
{
    __shared__ float xs[64][65];
    __shared__ float Wt[64][65];
    __shared__ float sred[4][64];
    __shared__ float dred[4][64];
    __shared__ float dtot[64];
    int tid = threadIdx.x, r0 = blockIdx.x * 64;
    int rb128 = blockIdx.x >> 1, half = blockIdx.x & 1;

    if (tid < 64) {
        float s = 0.f;
#pragma unroll
        for (int p = 0; p < NS; p++) s += denP[p * 8192 + r0 + tid];
        dtot[tid] = fmaxf(s, 1e-20f);
    }
    __syncthreads();
    for (int e = tid; e < 4096; e += 256) {
        int r = e >> 6;
        float s = 0.f;
#pragma unroll
        for (int p = 0; p < NS; p++)
            s += numP[(size_t)(p * 64 + rb128) * 8192 + half * 4096 + e];
        float v = s / dtot[r];
        xs[r][e & 63] = v > 0.f ? v : 0.f;
    }
    prep_tail(xs, Wt, sred, dred, W, bias, avec, WhT, E12, F1h, F2h, tid, r0);
}

// --------------------------- aggregation (core) ----------------------------
// grid (64, 16): 128-row block x 512-k split, 4 chunks of 128 k.
// MFMA 32x32x16 f16. A[m=lane&31][k=(lane>>5)*8+j];
// C/D: col=lane&31, row=(reg&3)+8*(reg>>2)+4*(lane>>5).
// WhBf fragment-order: slot(g,f) = g*64 + ((f+g)&63), g = k-octet (0..15/chunk).
struct AggSmem {
    uint4        WhBf[1024];                   // 16 KB: [g][f-rot] 8-half slots
    unsigned int mkAll[128][20];               // 10240 B (16 words used)
    unsigned int f1All[256];                   // 512 halves
    unsigned int f2All[256];                   // 512 halves
};                                             // 28672 B

__device__ __forceinline__ void agg_body(
    const unsigned int* __restrict__ bits,
    const _Float16* __restrict__ WhT, const unsigned int* __restrict__ E12,
    const _Float16* __restrict__ F1h, const _Float16* __restrict__ F2h,
    float* __restrict__ numP, float* __restrict__ denP)
{
    constexpr int CK = 128, NCH = 4;           // 512 k per block
    __shared__ AggSmem sm;

    int tid  = threadIdx.x;
    int wave = tid >> 6, lane = tid & 63;
    int l32 = lane & 31, khalf = lane >> 5;
    int rowblk = blockIdx.x, ks = blockIdx.y;
    int k0 = ks * (CK * NCH);

    // ---- masks: 128 rows x 16 words ----
#pragma unroll
    for (int j = 0; j < 2; j++) {
        int s = tid + 256 * j;
        int row_l = s >> 2, q = s & 3;
        uint4 v = *reinterpret_cast<const uint4*>(
            bits + (size_t)(rowblk * 128 + row_l) * 256 + ks * 16 + q * 4);
        *reinterpret_cast<uint4*>(&sm.mkAll[row_l][q * 4]) = v;
    }
    // ---- exp tables for the 512-k range ----
    if (tid < 64) {
        uint4 v = *reinterpret_cast<const uint4*>(F1h + k0 + tid * 8);
        *reinterpret_cast<uint4*>(&sm.f1All[tid * 4]) = v;
    } else if (tid < 128) {
        int t2 = tid - 64;
        uint4 v = *reinterpret_cast<const uint4*>(F2h + k0 + t2 * 8);
        *reinterpret_cast<uint4*>(&sm.f2All[t2 * 4]) = v;
    }

    // ---- WhBf staging: thread t covers (f=t>>3 [+32], g=t&7 [+8]) ----
    uint4 P[4];
#pragma unroll
    for (int i = 0; i < 4; i++) {
        int ff = (tid >> 3) + (i & 1) * 32, gg = (tid & 7) + (i >> 1) * 8;
        P[i] = *reinterpret_cast<const uint4*>(WhT + (size_t)ff * 8192 + k0 + gg * 8);
    }
#pragma unroll
    for (int i = 0; i < 4; i++) {
        int ff = (tid >> 3) + (i & 1) * 32, gg = (tid & 7) + (i >> 1) * 8;
        sm.WhBf[gg * 64 + ((ff + gg) & 63)] = P[i];
    }
    __syncthreads();

    int row = rowblk * 128 + wave * 32 + l32;
    int lrow = wave * 32 + l32;
    unsigned int e12 = E12[row];
    HV2 e1p, e2p;
    e1p.u = (e12 & 0xFFFFu);  e1p.u |= e1p.u << 16;   // {e^s, e^s}
    e2p.u = (e12 >> 16);      e2p.u |= e2p.u << 16;   // {e^.2s, e^.2s}

    f32x16 acc0 = {}, acc1 = {}, accd = {};

    Frag16 ones;
    ones.u[0] = ones.u[1] = ones.u[2] = ones.u[3] = 0x3C003C00u;  // f16 1.0

    for (int c = 0; c < NCH; c++) {
        if (c + 1 < NCH) {                     // prefetch next chunk's WhT
            int kc = k0 + (c + 1) * CK;
#pragma unroll
            for (int i = 0; i < 4; i++) {
                int ff = (tid >> 3) + (i & 1) * 32, gg = (tid & 7) + (i >> 1) * 8;
                P[i] = *reinterpret_cast<const uint4*>(
                    WhT + (size_t)ff * 8192 + kc + gg * 8);
            }
        }

#pragma unroll
        for (int kb = 0; kb < CK; kb += 16) {
            int wi = kb + khalf * 8;           // lane's k-offset in chunk
            unsigned int word = sm.mkAll[lrow][c * 4 + (wi >> 5)];
            unsigned int w8 = word >> (wi & 31);

            int fidx = (c * CK + wi) >> 1;     // uint index into f tables
            uint4 f1v = *reinterpret_cast<const uint4*>(&sm.f1All[fidx]);
            uint4 f2v = *reinterpret_cast<const uint4*>(&sm.f2All[fidx]);
            unsigned int f1a[4] = {f1v.x, f1v.y, f1v.z, f1v.w};
            unsigned int f2a[4] = {f2v.x, f2v.y, f2v.z, f2v.w};

            Frag16 A;
#pragma unroll
            for (int p = 0; p < 4; p++) {
                HV2 fa, fb, wa;
                fa.u = f1a[p];
                fb.u = f2a[p];
                // exp(lrelu(s+d)) = max(e^s e^d, e^.2s e^.2d)
                wa.v = __builtin_elementwise_max(e1p.v * fa.v, e2p.v * fb.v);
                int s0 = ((int)(w8 << (31 - 2 * p))) >> 31;   // sext bit 2p
                int s1 = ((int)(w8 << (30 - 2 * p))) >> 31;   // sext bit 2p+1
                unsigned int pm = ((unsigned)s0 & 0xFFFFu) | ((unsigned)s1 << 16);
                A.u[p] = wa.u & pm;
            }

            int g0 = (kb >> 3) + khalf;        // lane's k-octet index
            Frag16 B0, B1;
            B0.v = *reinterpret_cast<const f16x8*>(
                &sm.WhBf[g0 * 64 + ((l32 + g0) & 63)]);
            B1.v = *reinterpret_cast<const f16x8*>(
                &sm.WhBf[g0 * 64 + ((32 + l32 + g0) & 63)]);
            acc0 = __builtin_amdgcn_mfma_f32_32x32x16_f16(A.v, B0.v, acc0, 0, 0, 0);
            acc1 = __builtin_amdgcn_mfma_f32_32x32x16_f16(A.v, B1.v, acc1, 0, 0, 0);
            accd = __builtin_amdgcn_mfma_f32_32x32x16_f16(A.v, ones.v, accd, 0, 0, 0);
        }

        if (c + 1 < NCH) {
            __syncthreads();                   // done reading chunk c
#pragma unroll
            for (int i = 0; i < 4; i++) {
                int ff = (tid >> 3) + (i & 1) * 32, gg = (tid & 7) + (i >> 1) * 8;
                sm.WhBf[gg * 64 + ((ff + gg) & 63)] = P[i];
            }
            __syncthreads();                   // chunk c+1 visible
        }
    }

    // ---- epilogue: direct coalesced stores (each inst = 2 full sectors) ----
    float* tile = numP + (size_t)(ks * 64 + rowblk) * 8192;
#pragma unroll
    for (int r = 0; r < 16; r++) {
        int rl = wave * 32 + (r & 3) + 8 * (r >> 2) + 4 * khalf;
        tile[rl * 64 + l32]      = acc0[r];
        tile[rl * 64 + 32 + l32] = acc1[r];
        if (l32 == 0)
            denP[ks * 8192 + rowblk * 128 + rl] = accd[r];
    }
}

__global__ __launch_bounds__(256) void k_agg_l0(
    const unsigned int* __restrict__ bits,
    const _Float16* __restrict__ WhT, const unsigned int* __restrict__ E12,
    const _Float16* __restrict__ F1h, const _Float16* __restrict__ F2h,
    float* __restrict__ numP, float* __restrict__ denP)
{
    agg_body(bits, WhT, E12, F1h, F2h, numP, denP);
}

__global__ __launch_bounds__(256) void k_agg_l1(
    const unsigned int* __restrict__ bits,
    const _Float16* __restrict__ WhT, const unsigned int* __restrict__ E12,
    const _Float16* __restrict__ F1h, const _Float16* __restrict__ F2h,
    float* __restrict__ numP, float* __restrict__ denP)
{
    agg_body(bits, WhT, E12, F1h, F2h, numP, denP);
}

// ----------------------------- output GEMM ---------------------------------
template <int NS>
__global__ __launch_bounds__(256) void k_out(
    const float* __restrict__ numP, const float* __restrict__ denP,
    const float* __restrict__ W, const float* __restrict__ bias,
    float* __restrict__ out)
{
    __shared__ float xs[64][65];
    __shared__ float Wt[64][65];
    __shared__ float dtot[64];
    int tid = threadIdx.x, r0 = blockIdx.x * 64;
    int rb128 = blockIdx.x >> 1, half = blockIdx.x & 1;

    if (tid < 64) {
        float s = 0.f;
#pragma unroll
        for (int p = 0; p < NS; p++) s += denP[p * 8192 + r0 + tid];
        dtot[tid] = fmaxf(s, 1e-20f);
    }
    __syncthreads();
    for (int e = tid; e < 4096; e += 256) {
        int r = e >> 6;
        float s = 0.f;
#pragma unroll
        for (int p = 0; p < NS; p++)
            s += numP[(size_t)(p * 64 + rb128) * 8192 + half * 4096 + e];
        float v = s / dtot[r];
        xs[r][e & 63] = v > 0.f ? v : 0.f;
    }
    for (int e = tid; e < 4096; e += 256) {
        int o = e >> 6, c = e & 63;
        Wt[c][o] = W[e];
    }
    __syncthreads();

    int r = tid & 63, chunk = tid >> 6, c0 = chunk * 16;
    float acc[16];
#pragma unroll
    for (int o = 0; o < 16; o++) acc[o] = bias[c0 + o];
    for (int c = 0; c < 64; c++) {
        float xv = xs[r][c];
#pragma unroll
        for (int o = 0; o < 16; o++) acc[o] += xv * Wt[c][c0 + o];
    }
#pragma unroll
    for (int o = 0; o < 16; o++)
        out[(r0 + r) * 64 + c0 + o] = acc[o];
}

// ------------------------------- launch ------------------------------------
extern "C" void kernel_launch(void* const* d_in, const int* in_sizes, int n_in,
                              void* d_out, int out_size, void* d_ws, size_t ws_size,
                              hipStream_t stream)
{
    const int*   adj = (const int*)d_in[0];
    const float* ue  = (const float*)d_in[1];
    const float* ie  = (const float*)d_in[2];
    const float* W0w = (const float*)d_in[3];
    const float* W0b = (const float*)d_in[4];
    const float* a0  = (const float*)d_in[5];
    const float* W1w = (const float*)d_in[6];
    const float* W1b = (const float*)d_in[7];
    const float* a1  = (const float*)d_in[8];
    const float* Ow  = (const float*)d_in[9];
    const float* Ob  = (const float*)d_in[10];

    constexpr int NS = 16;

    char* ws = (char*)d_ws;
    size_t off = 0;
    auto alloc = [&](size_t bytes) -> char* {
        char* p = ws + off;
        off += (bytes + 255) & ~(size_t)255;
        return p;
    };
    float*        numP    = (float*)alloc((size_t)NS * 64 * 8192 * 4);  // 32 MB
    float*        denP    = (float*)alloc((size_t)NS * 8192 * 4);       // 512 KB
    unsigned long long* adjbits = (unsigned long long*)alloc(8192 * 1024); // 8 MB
    _Float16*     WhT0    = (_Float16*)alloc(64 * 8192 * 2);            // 1 MB
    _Float16*     WhT1    = (_Float16*)alloc(64 * 8192 * 2);            // 1 MB
    unsigned int* E12_0   = (unsigned int*)alloc(8192 * 4);
    unsigned int* E12_1   = (unsigned int*)alloc(8192 * 4);
    _Float16* F1h0 = (_Float16*)alloc(8192 * 2);
    _Float16* F2h0 = (_Float16*)alloc(8192 * 2);
    _Float16* F1h1 = (_Float16*)alloc(8192 * 2);
    _Float16* F2h1 = (_Float16*)alloc(8192 * 2);
    // ~43 MB total; every buffer fully overwritten each launch (0xAA-safe).

    const unsigned int* bits32 = (const unsigned int*)adjbits;

    // stream adj -> bitmask (the only full 256 MB read of the pipeline)
    k_pack<<<2048, 256, 0, stream>>>(adj, adjbits);

    // layer 0
    k_prep0<<<128, 256, 0, stream>>>(ue, ie, W0w, W0b, a0,
                                     WhT0, E12_0, F1h0, F2h0);
    k_agg_l0<<<dim3(64, NS), 256, 0, stream>>>(bits32, WhT0, E12_0,
                                               F1h0, F2h0, numP, denP);
    // layer 1
    k_prep1<NS><<<128, 256, 0, stream>>>(numP, denP, W1w, W1b, a1,
                                         WhT1, E12_1, F1h1, F2h1);
    k_agg_l1<<<dim3(64, NS), 256, 0, stream>>>(bits32, WhT1, E12_1,
                                               F1h1, F2h1, numP, denP);
    // output projection
    k_out<NS><<<128, 256, 0, stream>>>(numP, denP, Ow, Ob, (float*)d_out);
}